// Round 1
// baseline (5850.953 us; speedup 1.0000x reference)
//
#include <hip/hip_runtime.h>
#include <cmath>

// Problem constants (from reference setup_inputs)
#define B_   2048
#define S_   64
#define H_   256
#define NSTEP 32
#define OUT_S (NSTEP + 1)   // 33

// Tiling
#define BM  32   // batch rows per block
#define BNJ 32   // h-columns per block (each has 4 gate columns)
#define KC  32   // K chunk

__device__ __forceinline__ float fast_sigmoid(float x) {
    return 1.f / (1.f + __expf(-x));
}
__device__ __forceinline__ float fast_tanh(float x) {
    // tanh(x) = 1 - 2/(1+exp(2x)); saturates correctly for |x| large
    return 1.f - 2.f / (1.f + __expf(2.f * x));
}

// One LSTM step, fused: gates = x@W_ih^T + h@W_hh^T + (b_ih+b_hh); cell update.
// For the AR phase pass x = h_in (x_stride = H_), which gives h@(W_ih+W_hh)^T.
__global__ __launch_bounds__(256) void lstm_step_kernel(
    const float* __restrict__ x, int x_stride,      // [B, >=H], row stride x_stride
    const float* __restrict__ h_in,                 // [B, H]
    float* __restrict__ h_out,                      // [B, H]
    float* __restrict__ c,                          // [B, H], in-place
    const float* __restrict__ W_ih,                 // [4H, H]
    const float* __restrict__ W_hh,                 // [4H, H]
    const float* __restrict__ b_ih,                 // [4H]
    const float* __restrict__ b_hh,                 // [4H]
    float* __restrict__ out_h)                      // may be null; row stride OUT_S*H_
{
    // float4 rows with +1 float4 pad to spread LDS banks
    __shared__ float4 sX[BM][KC / 4 + 1];        // 32 x 9 float4
    __shared__ float4 sW[4 * BNJ][KC / 4 + 1];   // 128 x 9 float4

    const int tid = threadIdx.x;
    const int tj  = tid & 31;   // j within tile
    const int tb4 = tid >> 5;   // 0..7 -> handles rows tb4*4 .. tb4*4+3
    const int b0  = blockIdx.x * BM;
    const int j0  = blockIdx.y * BNJ;

    float acc[4][4];
#pragma unroll
    for (int r = 0; r < 4; ++r)
#pragma unroll
        for (int g = 0; g < 4; ++g) acc[r][g] = 0.f;

    for (int kc = 0; kc < 2 * H_; kc += KC) {
        const bool from_h = (kc >= H_);
        const int kbase = from_h ? (kc - H_) : kc;
        const float* srcX = from_h ? h_in : x;
        const int strideX = from_h ? H_ : x_stride;
        const float* srcW = from_h ? W_hh : W_ih;

        // stage X/H chunk: 32 rows x 32 k (4 floats per thread, coalesced)
#pragma unroll
        for (int i = 0; i < 4; ++i) {
            int lin = tid + i * 256;
            int row = lin >> 5;
            int kk  = lin & 31;
            ((float*)&sX[row][0])[kk] =
                srcX[(size_t)(b0 + row) * strideX + kbase + kk];
        }
        // stage W chunk: 128 gate-cols x 32 k (16 floats per thread, coalesced)
#pragma unroll
        for (int i = 0; i < 16; ++i) {
            int lin  = tid + i * 256;
            int row  = lin >> 5;          // c_local 0..127
            int kk   = lin & 31;
            int gate = row >> 5;          // 0..3
            int jj   = row & 31;
            int cg   = gate * H_ + j0 + jj;
            ((float*)&sW[row][0])[kk] = srcW[(size_t)cg * H_ + kbase + kk];
        }
        __syncthreads();

#pragma unroll
        for (int k4 = 0; k4 < KC / 4; ++k4) {
            float4 xr[4], wv[4];
#pragma unroll
            for (int r = 0; r < 4; ++r) xr[r] = sX[tb4 * 4 + r][k4];
#pragma unroll
            for (int g = 0; g < 4; ++g) wv[g] = sW[g * 32 + tj][k4];
#pragma unroll
            for (int r = 0; r < 4; ++r)
#pragma unroll
                for (int g = 0; g < 4; ++g) {
                    acc[r][g] += xr[r].x * wv[g].x;
                    acc[r][g] += xr[r].y * wv[g].y;
                    acc[r][g] += xr[r].z * wv[g].z;
                    acc[r][g] += xr[r].w * wv[g].w;
                }
        }
        __syncthreads();
    }

    // epilogue: bias + activations + cell update
    const int j = j0 + tj;
    float bsum[4];
#pragma unroll
    for (int g = 0; g < 4; ++g) bsum[g] = b_ih[g * H_ + j] + b_hh[g * H_ + j];

#pragma unroll
    for (int r = 0; r < 4; ++r) {
        const int b = b0 + tb4 * 4 + r;
        float pi = acc[r][0] + bsum[0];
        float pf = acc[r][1] + bsum[1];
        float pg = acc[r][2] + bsum[2];
        float po = acc[r][3] + bsum[3];
        float ig = fast_sigmoid(pi);
        float fg = fast_sigmoid(pf);
        float gg = fast_tanh(pg);
        float og = fast_sigmoid(po);
        size_t idx = (size_t)b * H_ + j;
        float cn = fg * c[idx] + ig * gg;
        float hn = og * fast_tanh(cn);
        c[idx] = cn;
        h_out[idx] = hn;
        if (out_h) out_h[(size_t)b * (OUT_S * H_) + j] = hn;
    }
}

extern "C" void kernel_launch(void* const* d_in, const int* in_sizes, int n_in,
                              void* d_out, int out_size, void* d_ws, size_t ws_size,
                              hipStream_t stream) {
    const float* x0   = (const float*)d_in[0];
    const float* W_ih = (const float*)d_in[1];
    const float* W_hh = (const float*)d_in[2];
    const float* b_ih = (const float*)d_in[3];
    const float* b_hh = (const float*)d_in[4];
    float* out = (float*)d_out;

    // workspace: h ping-pong (2 x 2MB) + c (2MB)
    float* h0 = (float*)d_ws;
    float* h1 = h0 + (size_t)B_ * H_;
    float* cc = h1 + (size_t)B_ * H_;

    hipMemsetAsync(h0, 0, (size_t)B_ * H_ * sizeof(float), stream);
    hipMemsetAsync(cc, 0, (size_t)B_ * H_ * sizeof(float), stream);

    dim3 grid(B_ / BM, H_ / BNJ);   // (64, 8) = 512 blocks
    dim3 block(256);
    float* hbuf[2] = {h0, h1};

    // ---- encoder: 64 steps over x_0 ----
    for (int t = 0; t < S_; ++t) {
        float* oh = (t == S_ - 1) ? out : nullptr;  // s = 0 slot
        lstm_step_kernel<<<grid, block, 0, stream>>>(
            x0 + (size_t)t * H_, S_ * H_,
            hbuf[t & 1], hbuf[(t + 1) & 1], cc,
            W_ih, W_hh, b_ih, b_hh, oh);
    }
    // ---- autoregressive rollout: 32 steps, x = h ----
    for (int t = 0; t < NSTEP; ++t) {
        int p = t & 1;  // S_ is even, so parity continues cleanly
        lstm_step_kernel<<<grid, block, 0, stream>>>(
            hbuf[p], H_,
            hbuf[p], hbuf[p ^ 1], cc,
            W_ih, W_hh, b_ih, b_hh, out + (size_t)(t + 1) * H_);
    }
}

// Round 2
// 1756.909 us; speedup vs baseline: 3.3303x; 3.3303x over previous
//
#include <hip/hip_runtime.h>
#include <cstdint>
#include <cstddef>

// Problem constants
#define B_    2048
#define H_    256
#define S_    64
#define NSTEP 32
#define OUTS  (NSTEP + 1)   // 33
#define N4H   1024          // 4*H gate columns (permuted: n = j*4 + g)

#define LOSCALE     2048.0f       // 2^11: keeps lo-parts out of f16 denormal range
#define INV_LOSCALE (1.0f/2048.0f)

typedef _Float16 f16;
typedef _Float16 f16x8 __attribute__((ext_vector_type(8)));
typedef _Float16 f16x4 __attribute__((ext_vector_type(4)));
typedef float    f32x4 __attribute__((ext_vector_type(4)));

__device__ __forceinline__ float sigm(float x)  { return 1.f / (1.f + __expf(-x)); }
__device__ __forceinline__ float tanh_(float x) { return 1.f - 2.f / (1.f + __expf(2.f * x)); }

// ---------------------------------------------------------------------------
// Prep: pack weights into gate-interleaved [n = j*4+g][k] split-f16 layout.
//  - WeH/WeL: encoder weights, K=512 ([W_ih | W_hh] along k)
//  - WaH/WaL: AR weights, K=256 (W_ih + W_hh pre-summed, since x == h)
//  - pb: permuted bias sum
// ---------------------------------------------------------------------------
__global__ __launch_bounds__(256) void prep_kernel(
    const float* __restrict__ W_ih, const float* __restrict__ W_hh,
    const float* __restrict__ b_ih, const float* __restrict__ b_hh,
    f16* __restrict__ WeH, f16* __restrict__ WeL,
    f16* __restrict__ WaH, f16* __restrict__ WaL,
    float* __restrict__ pb)
{
    int t = blockIdx.x * 256 + threadIdx.x;
    if (t < N4H * 512) {
        int n = t >> 9, k = t & 511;
        int j = n >> 2, g = n & 3;
        float w = (k < H_) ? W_ih[(size_t)(g * H_ + j) * H_ + k]
                           : W_hh[(size_t)(g * H_ + j) * H_ + (k - H_)];
        f16 hi = (f16)w;
        WeH[t] = hi;
        WeL[t] = (f16)((w - (float)hi) * LOSCALE);
    } else if (t < N4H * 512 + N4H * H_) {
        int u = t - N4H * 512;
        int n = u >> 8, k = u & 255;
        int j = n >> 2, g = n & 3;
        float w = W_ih[(size_t)(g * H_ + j) * H_ + k] + W_hh[(size_t)(g * H_ + j) * H_ + k];
        f16 hi = (f16)w;
        WaH[u] = hi;
        WaL[u] = (f16)((w - (float)hi) * LOSCALE);
    } else if (t < N4H * 512 + N4H * H_ + N4H) {
        int n = t - (N4H * 512 + N4H * H_);
        int j = n >> 2, g = n & 3;
        pb[n] = b_ih[g * H_ + j] + b_hh[g * H_ + j];
    }
}

// ---------------------------------------------------------------------------
// One LSTM step: gates[2048,1024] = [x|h] @ Wp^T via split-f16 MFMA, fused
// sigmoid/tanh cell update in the epilogue.
//   A rows = batch, B rows = permuted gate-cols (n = j*4+g), k contiguous.
//   Block tile 64(M)x64(N), BK=32, 4 waves each computing a 32x32 subtile
//   (2x2 frags of mfma_f32_16x16x32_f16).
// For k <  KX: A source is fp32 x (converted+split in staging).
// For k >= KX: A source is split-f16 h (hHi/hLo).
// ---------------------------------------------------------------------------
__global__ __launch_bounds__(256) void lstm_step_mfma(
    const float* __restrict__ xA, int xStride,
    const f16* __restrict__ hHi, const f16* __restrict__ hLo,
    const f16* __restrict__ WHi, const f16* __restrict__ WLo,
    int K, int KX,
    const float* __restrict__ pb, float* __restrict__ c,
    f16* __restrict__ hOutHi, f16* __restrict__ hOutLo,
    float* __restrict__ outF)   // nullable; row stride OUTS*H_
{
    __shared__ __align__(16) f16 sAhi[64 * 32];
    __shared__ __align__(16) f16 sAlo[64 * 32];
    __shared__ __align__(16) f16 sBhi[64 * 32];
    __shared__ __align__(16) f16 sBlo[64 * 32];
    __shared__ float sEpi[4][32][33];   // per-wave 32x32 fp32 tile, padded

    const int tid  = threadIdx.x;
    const int l    = tid & 63;
    const int w    = tid >> 6;
    const int wrow = (w >> 1) * 32;     // wave subtile row offset (M)
    const int wcol = (w & 1) * 32;      // wave subtile col offset (N)
    const int b0 = blockIdx.x * 64;
    const int n0 = blockIdx.y * 64;

    // staging: thread -> (row = tid>>2, k-chunk = (tid&3)*8); LDS linear at tid*16B
    const int arow = tid >> 2;
    const int acol = (tid & 3) * 8;

    // MFMA fragment lane decode (16x16x32: elem k = quad*8+j, row/col = lane&15)
    const int fr = l & 15;
    const int q  = l >> 4;

    f32x4 accM[2][2], accL[2][2];
#pragma unroll
    for (int i = 0; i < 2; ++i)
#pragma unroll
        for (int j2 = 0; j2 < 2; ++j2) {
            accM[i][j2] = (f32x4){0.f, 0.f, 0.f, 0.f};
            accL[i][j2] = (f32x4){0.f, 0.f, 0.f, 0.f};
        }

    for (int kc = 0; kc < K; kc += 32) {
        __syncthreads();   // protect previous iter's LDS reads
        // ---- stage B (weights, already split f16) ----
        {
            size_t off = (size_t)(n0 + arow) * K + kc + acol;
            *(f16x8*)&sBhi[tid * 8] = *(const f16x8*)&WHi[off];
            *(f16x8*)&sBlo[tid * 8] = *(const f16x8*)&WLo[off];
        }
        // ---- stage A ----
        if (kc < KX) {  // fp32 x source: convert + split in flight
            const float* src = xA + (size_t)(b0 + arow) * xStride + kc + acol;
            float4 v0 = *(const float4*)src;
            float4 v1 = *(const float4*)(src + 4);
            float vals[8] = {v0.x, v0.y, v0.z, v0.w, v1.x, v1.y, v1.z, v1.w};
            f16x8 h8, l8;
#pragma unroll
            for (int e = 0; e < 8; ++e) {
                f16 hv = (f16)vals[e];
                h8[e] = hv;
                l8[e] = (f16)((vals[e] - (float)hv) * LOSCALE);
            }
            *(f16x8*)&sAhi[tid * 8] = h8;
            *(f16x8*)&sAlo[tid * 8] = l8;
        } else {        // split-f16 h source
            size_t off = (size_t)(b0 + arow) * H_ + (kc - KX) + acol;
            *(f16x8*)&sAhi[tid * 8] = *(const f16x8*)&hHi[off];
            *(f16x8*)&sAlo[tid * 8] = *(const f16x8*)&hLo[off];
        }
        __syncthreads();

        // ---- fragments + MFMA ----
        f16x8 aH[2], aL[2], bH[2], bL[2];
#pragma unroll
        for (int fm = 0; fm < 2; ++fm) {
            int row = wrow + fm * 16 + fr;
            aH[fm] = *(const f16x8*)&sAhi[row * 32 + q * 8];
            aL[fm] = *(const f16x8*)&sAlo[row * 32 + q * 8];
        }
#pragma unroll
        for (int fn = 0; fn < 2; ++fn) {
            int row = wcol + fn * 16 + fr;
            bH[fn] = *(const f16x8*)&sBhi[row * 32 + q * 8];
            bL[fn] = *(const f16x8*)&sBlo[row * 32 + q * 8];
        }
#pragma unroll
        for (int fm = 0; fm < 2; ++fm)
#pragma unroll
            for (int fn = 0; fn < 2; ++fn) {
                accM[fm][fn] = __builtin_amdgcn_mfma_f32_16x16x32_f16(aH[fm], bH[fn], accM[fm][fn], 0, 0, 0);
                accL[fm][fn] = __builtin_amdgcn_mfma_f32_16x16x32_f16(aH[fm], bL[fn], accL[fm][fn], 0, 0, 0);
                accL[fm][fn] = __builtin_amdgcn_mfma_f32_16x16x32_f16(aL[fm], bH[fn], accL[fm][fn], 0, 0, 0);
            }
    }

    // ---- epilogue: C-layout (col=lane&15, row=quad*4+reg) -> LDS -> cell ----
#pragma unroll
    for (int fm = 0; fm < 2; ++fm)
#pragma unroll
        for (int fn = 0; fn < 2; ++fn)
#pragma unroll
            for (int r = 0; r < 4; ++r) {
                float v = accM[fm][fn][r] + accL[fm][fn][r] * INV_LOSCALE;
                sEpi[w][fm * 16 + q * 4 + r][fn * 16 + fr] = v;
            }
    __syncthreads();

    // each lane: one batch row (er), 4 consecutive j's (jh half)
    const int er = l >> 1;
    const int jh = l & 1;
    const int bg = b0 + wrow + er;                       // global batch row
    const int jb = (n0 >> 2) + (wcol >> 2) + jh * 4;     // global j base (4 consecutive)
    const int pbase = n0 + wcol + jh * 16;               // permuted-n base for bias

    f32x4 c4 = *(const f32x4*)(c + (size_t)bg * H_ + jb);
    f32x4 o4, cn4;
    f16x4 hh4, hl4;
#pragma unroll
    for (int qq = 0; qq < 4; ++qq) {
        int col = jh * 16 + qq * 4;    // col within wave tile (j fast over 4 gates)
        float vi = sEpi[w][er][col + 0] + pb[pbase + qq * 4 + 0];
        float vf = sEpi[w][er][col + 1] + pb[pbase + qq * 4 + 1];
        float vg = sEpi[w][er][col + 2] + pb[pbase + qq * 4 + 2];
        float vo = sEpi[w][er][col + 3] + pb[pbase + qq * 4 + 3];
        float ig = sigm(vi), fg = sigm(vf), gg = tanh_(vg), og = sigm(vo);
        float cn = fg * c4[qq] + ig * gg;
        float hn = og * tanh_(cn);
        cn4[qq] = cn;
        o4[qq]  = hn;
        f16 hhi = (f16)hn;
        hh4[qq] = hhi;
        hl4[qq] = (f16)((hn - (float)hhi) * LOSCALE);
    }
    *(f32x4*)(c + (size_t)bg * H_ + jb) = cn4;
    *(f16x4*)(hOutHi + (size_t)bg * H_ + jb) = hh4;
    *(f16x4*)(hOutLo + (size_t)bg * H_ + jb) = hl4;
    if (outF) *(f32x4*)(outF + (size_t)bg * (OUTS * H_) + jb) = o4;
}

// ---------------------------------------------------------------------------
extern "C" void kernel_launch(void* const* d_in, const int* in_sizes, int n_in,
                              void* d_out, int out_size, void* d_ws, size_t ws_size,
                              hipStream_t stream) {
    const float* x0   = (const float*)d_in[0];
    const float* W_ih = (const float*)d_in[1];
    const float* W_hh = (const float*)d_in[2];
    const float* b_ih = (const float*)d_in[3];
    const float* b_hh = (const float*)d_in[4];
    float* out = (float*)d_out;

    // workspace layout (~9 MB)
    char* p = (char*)d_ws;
    float* cc = (float*)p; p += (size_t)B_ * H_ * 4;     // c, fp32
    float* pb = (float*)p; p += (size_t)N4H * 4;         // permuted bias
    f16* hH[2]; f16* hL[2];
    hH[0] = (f16*)p; p += (size_t)B_ * H_ * 2;
    hL[0] = (f16*)p; p += (size_t)B_ * H_ * 2;
    hH[1] = (f16*)p; p += (size_t)B_ * H_ * 2;
    hL[1] = (f16*)p; p += (size_t)B_ * H_ * 2;
    f16* WeH = (f16*)p; p += (size_t)N4H * 512 * 2;
    f16* WeL = (f16*)p; p += (size_t)N4H * 512 * 2;
    f16* WaH = (f16*)p; p += (size_t)N4H * H_ * 2;
    f16* WaL = (f16*)p; p += (size_t)N4H * H_ * 2;

    hipMemsetAsync(cc, 0, (size_t)B_ * H_ * 4, stream);
    hipMemsetAsync(hH[0], 0, (size_t)B_ * H_ * 2 * 2, stream);  // hH[0]+hL[0] contiguous

    int prep_total = N4H * 512 + N4H * H_ + N4H;
    prep_kernel<<<dim3((prep_total + 255) / 256), dim3(256), 0, stream>>>(
        W_ih, W_hh, b_ih, b_hh, WeH, WeL, WaH, WaL, pb);

    dim3 grid(B_ / 64, N4H / 64);   // (32, 16) = 512 blocks, 2/CU
    dim3 block(256);

    // ---- encoder: 64 steps, K=512 ([x_t | h]) ----
    for (int t = 0; t < S_; ++t) {
        lstm_step_mfma<<<grid, block, 0, stream>>>(
            x0 + (size_t)t * H_, S_ * H_,
            hH[t & 1], hL[t & 1], WeH, WeL, 512, 256,
            pb, cc, hH[(t + 1) & 1], hL[(t + 1) & 1],
            (t == S_ - 1) ? out : nullptr);   // s=0 slot
    }
    // ---- AR rollout: 32 steps, K=256 (Wsum, x==h) ----
    for (int t = 0; t < NSTEP; ++t) {
        int p2 = t & 1;   // S_ even -> parity continues
        lstm_step_mfma<<<grid, block, 0, stream>>>(
            nullptr, 0,
            hH[p2], hL[p2], WaH, WaL, 256, 0,
            pb, cc, hH[p2 ^ 1], hL[p2 ^ 1],
            out + (size_t)(t + 1) * H_);
    }
}

// Round 3
// 958.960 us; speedup vs baseline: 6.1014x; 1.8321x over previous
//
#include <hip/hip_runtime.h>
#include <cstdint>
#include <cstddef>

// Problem constants
#define B_    2048
#define H_    256
#define S_    64
#define NSTEP 32
#define OUTS  33
#define N4H   1024            // 4*H gate cols, permuted n = j*4 + g
#define XROWSTRIDE (S_ * H_)  // x0 batch-row stride (fixed t)

typedef _Float16 f16;
typedef _Float16 f16x8 __attribute__((ext_vector_type(8)));
typedef float    f32x4 __attribute__((ext_vector_type(4)));

__device__ __forceinline__ float sigm(float x)  { return 1.f / (1.f + __expf(-x)); }
__device__ __forceinline__ float tanh_(float x) { return 1.f - 2.f / (1.f + __expf(2.f * x)); }

// ---------------------------------------------------------------------------
// Prep: quantize + pack weights into MFMA-B-fragment-major f16 layout:
//   dest[((ct*KT + kk)*64 + q*16 + c15)*8 + e] = W[n = ct*16+c15][k = kk*32+q*8+e]
// so a lane's fragment is one contiguous 16B global load.
//   WeP: encoder, KT=16, k in [0,512) = [W_ih | W_hh], n permuted j*4+g
//   WaP: AR, KT=8, W_ih + W_hh pre-summed (x == h in AR phase)
//   pb : permuted bias sum
// ---------------------------------------------------------------------------
__global__ __launch_bounds__(256) void prep_kernel(
    const float* __restrict__ W_ih, const float* __restrict__ W_hh,
    const float* __restrict__ b_ih, const float* __restrict__ b_hh,
    f16* __restrict__ WeP, f16* __restrict__ WaP, float* __restrict__ pb)
{
    int t = blockIdx.x * 256 + threadIdx.x;
    if (t < N4H * 64) {                 // encoder pack: 8 elems/thread
        int n  = t >> 6;                // permuted col 0..1023
        int kc = (t & 63) * 8;          // k base 0..504
        int j = n >> 2, g = n & 3;
        const float* src = (kc < H_) ? &W_ih[(size_t)(g * H_ + j) * H_ + kc]
                                     : &W_hh[(size_t)(g * H_ + j) * H_ + kc - H_];
        f16x8 v;
#pragma unroll
        for (int e = 0; e < 8; ++e) v[e] = (f16)src[e];
        int ct = n >> 4, c15 = n & 15, kk = kc >> 5, q = (kc >> 3) & 3;
        *(f16x8*)&WeP[((size_t)(ct * 16 + kk) * 64 + q * 16 + c15) * 8] = v;
    } else if (t < N4H * 64 + N4H * 32) {   // AR pack (Wsum), KT=8
        int u  = t - N4H * 64;
        int n  = u >> 5;
        int kc = (u & 31) * 8;
        int j = n >> 2, g = n & 3;
        const float* s1 = &W_ih[(size_t)(g * H_ + j) * H_ + kc];
        const float* s2 = &W_hh[(size_t)(g * H_ + j) * H_ + kc];
        f16x8 v;
#pragma unroll
        for (int e = 0; e < 8; ++e) v[e] = (f16)(s1[e] + s2[e]);
        int ct = n >> 4, c15 = n & 15, kk = kc >> 5, q = (kc >> 3) & 3;
        *(f16x8*)&WaP[((size_t)(ct * 8 + kk) * 64 + q * 16 + c15) * 8] = v;
    } else if (t < N4H * 64 + N4H * 32 + N4H) {
        int n = t - (N4H * 64 + N4H * 32);
        int j = n >> 2, g = n & 3;
        pb[n] = b_ih[g * H_ + j] + b_hh[g * H_ + j];
    }
}

// ---------------------------------------------------------------------------
// One LSTM step. Block tile M=32 x N=256 (4 waves x N64). B fragments held in
// VGPRs for the whole kernel (loaded coalesced from the packed layout).
// K-loop: 2 ds_read_b128 + 8 MFMA per wave per k-chunk. 3 barriers total.
//   KT=16, HASX=true : encoder, A = [x_t (fp32->f16) | h]
//   KT=8,  HASX=false: AR, A = h, W = pre-summed
// ---------------------------------------------------------------------------
template<int KT, bool HASX>
__global__ __launch_bounds__(256, 1) void step_kernel(
    const float* __restrict__ xA,      // x_t base (HASX), row stride XROWSTRIDE
    const f16*  __restrict__ hIn,      // [2048][256] f16
    const f16*  __restrict__ Wp,       // packed frags
    const float* __restrict__ pb,
    float* __restrict__ c,             // [2048][256] fp32, in-place (disjoint slices)
    f16*  __restrict__ hOut,
    float* __restrict__ outF)          // nullable; row stride OUTS*H_
{
    // sA (2*KT*64*8 f16 = 32 KB max) and sEpi (32*260 f32 = 33.3 KB) overlaid
    __shared__ __align__(16) unsigned char smem[32 * 260 * 4];
    f16*   sA   = (f16*)smem;
    float* sEpi = (float*)smem;

    const int tid = threadIdx.x;
    const int l   = tid & 63;
    const int w   = tid >> 6;
    const int b0  = blockIdx.x * 32;
    const int np  = blockIdx.y;

    // ---- B fragments: global (L2) -> VGPR, coalesced 16B per lane ----
    f16x8 Bf[4][KT];
#pragma unroll
    for (int f = 0; f < 4; ++f) {
        const int ct = np * 16 + w * 4 + f;
#pragma unroll
        for (int kk = 0; kk < KT; ++kk)
            Bf[f][kk] = *(const f16x8*)&Wp[((size_t)(ct * KT + kk) * 64 + l) * 8];
    }

    // ---- stage A slice (32 rows x K) into LDS, fragment-major ----
    {
        const int row  = tid >> 3;
        const int kseg = (tid & 7) * 32;
        const int mt = row >> 4, lrow = row & 15;
        if (HASX) {
            const float* src = xA + (size_t)(b0 + row) * XROWSTRIDE + kseg;
            const int kkA = kseg >> 5;           // x half: kk 0..7
#pragma unroll
            for (int q = 0; q < 4; ++q) {
                float4 v0 = *(const float4*)(src + q * 8);
                float4 v1 = *(const float4*)(src + q * 8 + 4);
                f16x8 h8;
                h8[0]=(f16)v0.x; h8[1]=(f16)v0.y; h8[2]=(f16)v0.z; h8[3]=(f16)v0.w;
                h8[4]=(f16)v1.x; h8[5]=(f16)v1.y; h8[6]=(f16)v1.z; h8[7]=(f16)v1.w;
                *(f16x8*)&sA[((size_t)(mt * KT + kkA) * 64 + q * 16 + lrow) * 8] = h8;
            }
            const f16* hsrc = hIn + (size_t)(b0 + row) * H_ + kseg;
            const int kkH = 8 + (kseg >> 5);     // h half: kk 8..15
#pragma unroll
            for (int q = 0; q < 4; ++q) {
                f16x8 h8 = *(const f16x8*)(hsrc + q * 8);
                *(f16x8*)&sA[((size_t)(mt * KT + kkH) * 64 + q * 16 + lrow) * 8] = h8;
            }
        } else {
            const f16* hsrc = hIn + (size_t)(b0 + row) * H_ + kseg;
            const int kkH = kseg >> 5;           // kk 0..7
#pragma unroll
            for (int q = 0; q < 4; ++q) {
                f16x8 h8 = *(const f16x8*)(hsrc + q * 8);
                *(f16x8*)&sA[((size_t)(mt * KT + kkH) * 64 + q * 16 + lrow) * 8] = h8;
            }
        }
    }
    __syncthreads();

    // ---- K loop: MFMA-bound (2 reads : 8 MFMAs per wave per kk) ----
    f32x4 acc[2][4];
#pragma unroll
    for (int fm = 0; fm < 2; ++fm)
#pragma unroll
        for (int f = 0; f < 4; ++f) acc[fm][f] = (f32x4){0.f, 0.f, 0.f, 0.f};

#pragma unroll
    for (int kk = 0; kk < KT; ++kk) {
        f16x8 a0 = *(const f16x8*)&sA[((size_t)(0 * KT + kk) * 64 + l) * 8];
        f16x8 a1 = *(const f16x8*)&sA[((size_t)(1 * KT + kk) * 64 + l) * 8];
#pragma unroll
        for (int f = 0; f < 4; ++f) {
            acc[0][f] = __builtin_amdgcn_mfma_f32_16x16x32_f16(a0, Bf[f][kk], acc[0][f], 0, 0, 0);
            acc[1][f] = __builtin_amdgcn_mfma_f32_16x16x32_f16(a1, Bf[f][kk], acc[1][f], 0, 0, 0);
        }
    }
    __syncthreads();   // sA dead; smem becomes sEpi

    // ---- epilogue: C layout (col = lane&15, row = quad*4 + r) -> LDS ----
    const int q = l >> 4, c15 = l & 15;
#pragma unroll
    for (int fm = 0; fm < 2; ++fm)
#pragma unroll
        for (int f = 0; f < 4; ++f) {
            const int nl = w * 64 + f * 16 + c15;
#pragma unroll
            for (int r = 0; r < 4; ++r)
                sEpi[(fm * 16 + q * 4 + r) * 260 + nl] = acc[fm][f][r];
        }
    __syncthreads();

    // ---- fused LSTM cell: thread -> (row, 8 consecutive j) ----
    {
        const int row = tid >> 3;
        const int ljb = (tid & 7) * 8;
        const int bg  = b0 + row;
        const int jg  = np * 64 + ljb;
        float cbuf[8], hbuf[8];
        f16 hf[8];
        *(f32x4*)&cbuf[0] = *(const f32x4*)&c[(size_t)bg * H_ + jg];
        *(f32x4*)&cbuf[4] = *(const f32x4*)&c[(size_t)bg * H_ + jg + 4];
#pragma unroll
        for (int jj = 0; jj < 8; ++jj) {
            const int nl = (ljb + jj) * 4;
            f32x4 g4 = *(const f32x4*)&sEpi[row * 260 + nl];
            const float* pbp = &pb[np * 256 + nl];
            float vi = g4[0] + pbp[0];
            float vf = g4[1] + pbp[1];
            float vg = g4[2] + pbp[2];
            float vo = g4[3] + pbp[3];
            float ig = sigm(vi), fg = sigm(vf), gg = tanh_(vg), og = sigm(vo);
            float cn = fg * cbuf[jj] + ig * gg;
            float hn = og * tanh_(cn);
            cbuf[jj] = cn; hbuf[jj] = hn; hf[jj] = (f16)hn;
        }
        *(f32x4*)&c[(size_t)bg * H_ + jg]     = *(f32x4*)&cbuf[0];
        *(f32x4*)&c[(size_t)bg * H_ + jg + 4] = *(f32x4*)&cbuf[4];
        *(f16x8*)&hOut[(size_t)bg * H_ + jg]  = *(f16x8*)&hf[0];
        if (outF) {
            *(f32x4*)&outF[(size_t)bg * (OUTS * H_) + jg]     = *(f32x4*)&hbuf[0];
            *(f32x4*)&outF[(size_t)bg * (OUTS * H_) + jg + 4] = *(f32x4*)&hbuf[4];
        }
    }
}

// ---------------------------------------------------------------------------
extern "C" void kernel_launch(void* const* d_in, const int* in_sizes, int n_in,
                              void* d_out, int out_size, void* d_ws, size_t ws_size,
                              hipStream_t stream) {
    const float* x0   = (const float*)d_in[0];
    const float* W_ih = (const float*)d_in[1];
    const float* W_hh = (const float*)d_in[2];
    const float* b_ih = (const float*)d_in[3];
    const float* b_hh = (const float*)d_in[4];
    float* out = (float*)d_out;

    // workspace (~5.6 MB)
    char* p = (char*)d_ws;
    float* cc = (float*)p; p += (size_t)B_ * H_ * 4;
    float* pb = (float*)p; p += (size_t)N4H * 4;
    f16* h0  = (f16*)p; p += (size_t)B_ * H_ * 2;
    f16* h1  = (f16*)p; p += (size_t)B_ * H_ * 2;
    f16* WeP = (f16*)p; p += (size_t)N4H * 512 * 2;
    f16* WaP = (f16*)p; p += (size_t)N4H * 256 * 2;

    hipMemsetAsync(cc, 0, (size_t)B_ * H_ * 4, stream);
    hipMemsetAsync(h0, 0, (size_t)B_ * H_ * 2, stream);

    const int prep_total = N4H * 64 + N4H * 32 + N4H;
    prep_kernel<<<dim3((prep_total + 255) / 256), dim3(256), 0, stream>>>(
        W_ih, W_hh, b_ih, b_hh, WeP, WaP, pb);

    dim3 grid(B_ / 32, N4H / 256);   // (64, 4) = 256 blocks, 1/CU
    dim3 blk(256);
    f16* hb[2] = {h0, h1};

    // ---- encoder: 64 steps, K=512 ----
    for (int t = 0; t < S_; ++t) {
        step_kernel<16, true><<<grid, blk, 0, stream>>>(
            x0 + (size_t)t * H_, hb[t & 1], WeP, pb, cc, hb[(t + 1) & 1],
            (t == S_ - 1) ? out : nullptr);   // s = 0 slot
    }
    // ---- AR rollout: 32 steps, K=256, x == h ----
    for (int t = 0; t < NSTEP; ++t) {
        const int pp = t & 1;   // S_ even -> parity continues
        step_kernel<8, false><<<grid, blk, 0, stream>>>(
            nullptr, hb[pp], WaP, pb, cc, hb[pp ^ 1],
            out + (size_t)(t + 1) * H_);
    }
}